// Round 8
// baseline (143.993 us; speedup 1.0000x reference)
//
#include <hip/hip_runtime.h>
#include <math.h>

#define NB   8
#define CIN  256
#define CMID 16
#define NH   128
#define NW   128
#define HWSZ 16384
#define HW4  4096
#define NANG 8
#define NRAD 9

typedef float    f32x4_t __attribute__((ext_vector_type(4)));
typedef unsigned u32x2_t __attribute__((ext_vector_type(2)));
typedef unsigned u32x4_t __attribute__((ext_vector_type(4)));

__device__ __forceinline__ unsigned short f2bf(float f) {
    unsigned u = __float_as_uint(f);
    u += 0x7fffu + ((u >> 16) & 1u);          // round-to-nearest-even
    return (unsigned short)(u >> 16);
}
__device__ __forceinline__ float bf_lo(unsigned u) { return __uint_as_float(u << 16); }
__device__ __forceinline__ float bf_hi(unsigned u) { return __uint_as_float(u & 0xffff0000u); }
__device__ __forceinline__ unsigned pack2(float a, float b) {
    return (unsigned)f2bf(a) | ((unsigned)f2bf(b) << 16);
}

__device__ __forceinline__ int bitrev7(int v) {
    return (int)(__brev((unsigned)v) >> 25);
}

// Gain in bit-reversed (both dims), ifftshift-folded order, pre-scaled by 1/16384.
__global__ void __launch_bounds__(256) gain_kernel(const float* __restrict__ fw,
                                                   float* __restrict__ gain) {
    int p  = blockIdx.x * 256 + threadIdx.x;
    int py = p >> 7, px = p & 127;
    int fy = bitrev7(py), fx = bitrev7(px);
    int hy = (fy + 64) & 127, hx = (fx + 64) & 127;
    float dy = (float)(hy - 64), dx = (float)(hx - 64);
    float r = sqrtf(dy * dy + dx * dx);
    int ridx = (int)floorf(r * 0.125f);
    if (ridx > NRAD - 1) ridx = NRAD - 1;
    const float PI_F = 3.14159265358979323846f;
    float theta = fmodf(atan2f(dy, dx) + PI_F, PI_F);
    const float delta = (float)(M_PI / 8.0);
    const float hwid  = (float)(1.5 * (M_PI / 8.0) / 2.0);
    float wv[NANG];
    float wsum = 0.f;
#pragma unroll
    for (int a = 0; a < NANG; ++a) {
        float c = ((float)a + 0.5f) * delta;
        float dist = fabsf(theta - c);
        float wa = fmaxf(1.0f - dist / hwid, 0.0f);
        if (!(dist < hwid)) wa = 0.0f;
        wv[a] = wa;
        wsum += wa;
    }
    float inv = 1.0f / (wsum + 1e-8f);
#pragma unroll
    for (int m = 0; m < CMID; ++m) {
        float g = 0.f;
#pragma unroll
        for (int a = 0; a < NANG; ++a)
            g += wv[a] * fw[(m * NANG + a) * NRAD + ridx];
        gain[m * HWSZ + p] = g * inv * (1.0f / 16384.0f);
    }
}

// K2: split-K projection, float4 lanes, 8 loads in flight, bf16 partial stores.
__global__ void __launch_bounds__(256, 4) proj_partial(const float* __restrict__ x,
                                                       const float* __restrict__ w_in,
                                                       unsigned short* __restrict__ partials,
                                                       int nchunk) {
    int b  = blockIdx.z;
    int ck = blockIdx.y;
    int p4 = blockIdx.x * 256 + threadIdx.x;          // float4 index, 4096/image
    int cpc = CIN / nchunk;
    int c0 = ck * cpc;
    const f32x4_t* xb = (const f32x4_t*)(x + (size_t)b * CIN * HWSZ);
    f32x4_t acc[CMID];
#pragma unroll
    for (int m = 0; m < CMID; ++m) acc[m] = (f32x4_t){0.f, 0.f, 0.f, 0.f};
    for (int c = c0; c < c0 + cpc; c += 8) {
        f32x4_t v[8];
#pragma unroll
        for (int k = 0; k < 8; ++k)
            v[k] = xb[(size_t)(c + k) * HW4 + p4];
#pragma unroll
        for (int k = 0; k < 8; ++k) {
#pragma unroll
            for (int m = 0; m < CMID; ++m)
                acc[m] += w_in[m * CIN + c + k] * v[k];
        }
    }
    ushort4* pb = (ushort4*)partials + ((size_t)(b * nchunk + ck) * CMID) * HW4;
#pragma unroll
    for (int m = 0; m < CMID; ++m)
        pb[(size_t)m * HW4 + p4] = make_ushort4(f2bf(acc[m].x), f2bf(acc[m].y),
                                                f2bf(acc[m].z), f2bf(acc[m].w));
}

// K3: reduce bf16 partials + forward row-DIF FFT.
__global__ void __launch_bounds__(256) reduce_fft_rows(const unsigned short* __restrict__ partials,
                                                       unsigned* __restrict__ xf,
                                                       int nchunk) {
    __shared__ float2 lds[512];
    int img = blockIdx.y;                             // b*16 + m
    int b = img >> 4, m = img & 15;
    int r0 = blockIdx.x * 4;
    int t = threadIdx.x;
    const unsigned* pbase = (const unsigned*)(partials +
        ((size_t)(b * nchunk) * CMID + m) * HWSZ + (size_t)r0 * NW) + t;
    size_t cks = (size_t)CMID * HWSZ / 2;             // uints per chunk
    float sx = 0.f, sy = 0.f;
    if (nchunk == 8) {
#pragma unroll
        for (int ck = 0; ck < 8; ++ck) {
            unsigned u = pbase[(size_t)ck * cks];
            sx += bf_lo(u); sy += bf_hi(u);
        }
    } else {
        for (int ck = 0; ck < nchunk; ++ck) {
            unsigned u = pbase[(size_t)ck * cks];
            sx += bf_lo(u); sy += bf_hi(u);
        }
    }
    lds[2 * t]     = make_float2(sx, 0.f);
    lds[2 * t + 1] = make_float2(sy, 0.f);
    __syncthreads();
    const float PI_F = 3.14159265358979323846f;
    int j = t & 63;
    float2* row = lds + (t >> 6) * 128;
    for (int ls = 6; ls >= 0; --ls) {
        int s = 1 << ls;
        int off = j & (s - 1);
        int i0 = ((j >> ls) << (ls + 1)) + off;
        float ang = -PI_F * (float)off / (float)s;
        float sn, cs;
        __sincosf(ang, &sn, &cs);
        float2 a = row[i0];
        float2 bb = row[i0 + s];
        row[i0] = make_float2(a.x + bb.x, a.y + bb.y);
        float dx_ = a.x - bb.x, dy_ = a.y - bb.y;
        row[i0 + s] = make_float2(dx_ * cs - dy_ * sn, dx_ * sn + dy_ * cs);
        __syncthreads();
    }
    unsigned* xo = xf + (size_t)img * HWSZ + (size_t)r0 * NW;
#pragma unroll
    for (int ii = 0; ii < 2; ++ii) {
        int px = ii * 256 + t;
        xo[px] = pack2(lds[px].x, lds[px].y);
    }
}

// K4: forward col-DIF + gain + inverse col-DIT on bf16-complex xf (in place).
__global__ void __launch_bounds__(256) fft_cols_gain(unsigned* __restrict__ xf,
                                                     const float* __restrict__ gain) {
    __shared__ float2 buf[128 * 33];
    int img = blockIdx.y;
    int m   = img & (CMID - 1);
    int c0  = blockIdx.x * 32;
    int t   = threadIdx.x;
    unsigned* xi = xf + (size_t)img * HWSZ;

    for (int idx = t; idx < 128 * 32; idx += 256) {
        int r = idx >> 5, lc = idx & 31;
        unsigned u = xi[r * NW + c0 + lc];
        buf[r * 33 + lc] = make_float2(bf_lo(u), bf_hi(u));
    }
    __syncthreads();
    const float PI_F = 3.14159265358979323846f;
    int lc = t & 31;
    int jb = t >> 5;
    for (int ls = 6; ls >= 0; --ls) {
        int s = 1 << ls;
        for (int j = jb; j < 64; j += 8) {
            int off = j & (s - 1);
            int i0 = ((j >> ls) << (ls + 1)) + off;
            float ang = -PI_F * (float)off / (float)s;
            float sn, cs;
            __sincosf(ang, &sn, &cs);
            float2 a = buf[i0 * 33 + lc];
            float2 bb = buf[(i0 + s) * 33 + lc];
            buf[i0 * 33 + lc] = make_float2(a.x + bb.x, a.y + bb.y);
            float dx_ = a.x - bb.x, dy_ = a.y - bb.y;
            buf[(i0 + s) * 33 + lc] = make_float2(dx_ * cs - dy_ * sn, dx_ * sn + dy_ * cs);
        }
        __syncthreads();
    }
    {
        const float* gm = gain + (size_t)m * HWSZ;
        for (int idx = t; idx < 128 * 32; idx += 256) {
            int r = idx >> 5, lcc = idx & 31;
            float g = gm[r * NW + c0 + lcc];
            buf[r * 33 + lcc].x *= g;
            buf[r * 33 + lcc].y *= g;
        }
        __syncthreads();
    }
    for (int ls = 0; ls <= 6; ++ls) {
        int s = 1 << ls;
        for (int j = jb; j < 64; j += 8) {
            int off = j & (s - 1);
            int i0 = ((j >> ls) << (ls + 1)) + off;
            float ang = PI_F * (float)off / (float)s;
            float sn, cs;
            __sincosf(ang, &sn, &cs);
            float2 a = buf[i0 * 33 + lc];
            float2 bb = buf[(i0 + s) * 33 + lc];
            float tx = bb.x * cs - bb.y * sn, ty = bb.x * sn + bb.y * cs;
            buf[i0 * 33 + lc] = make_float2(a.x + tx, a.y + ty);
            buf[(i0 + s) * 33 + lc] = make_float2(a.x - tx, a.y - ty);
        }
        __syncthreads();
    }
    for (int idx = t; idx < 128 * 32; idx += 256) {
        int r = idx >> 5, lcc = idx & 31;
        xi[r * NW + c0 + lcc] = pack2(buf[r * 33 + lcc].x, buf[r * 33 + lcc].y);
    }
}

// K5 (fused): inverse row-DIT for all 16 m of a 2-row strip + output GEMM.
// 512 threads: load phase (m=t>>5), FFT phase (8 waves x 4 rows), out phase
// (wave=c-group of 32, lanes=64 float4 positions). Final FFT stage writes
// packed-bf16 reals to ebf (stride-2B, conflict-free); out phase reads b64.
__global__ void __launch_bounds__(512, 4) ifft_out(const unsigned* __restrict__ xf,
                                                   const float* __restrict__ x,
                                                   const float* __restrict__ w_out,
                                                   float* __restrict__ out) {
    __shared__ float2 img[CMID * 256];            // 32 KB: [m][rr*128+px]
    __shared__ unsigned short ebf[CMID * 256];    // 8 KB packed bf16 reals
    int b  = blockIdx.y;
    int r0 = blockIdx.x * 2;
    int t  = threadIdx.x;
    {
        int m = t >> 5, q2 = t & 31;
        const unsigned* src = xf + ((size_t)(b * CMID + m)) * HWSZ + (size_t)r0 * NW + q2 * 8;
#pragma unroll
        for (int h = 0; h < 2; ++h) {
            u32x4_t u = *(const u32x4_t*)(src + h * 4);
#pragma unroll
            for (int k = 0; k < 4; ++k)
                img[m * 256 + q2 * 8 + h * 4 + k] = make_float2(bf_lo(u[k]), bf_hi(u[k]));
        }
    }
    __syncthreads();
    const float PI_F = 3.14159265358979323846f;
    int j = t & 63, f0 = t >> 6;                  // f0 in [0,8)
    for (int ls = 0; ls <= 5; ++ls) {
        int s = 1 << ls;
        int off = j & (s - 1);
        int i0 = ((j >> ls) << (ls + 1)) + off;
        float ang = PI_F * (float)off / (float)s;
        float sn, cs;
        __sincosf(ang, &sn, &cs);
#pragma unroll
        for (int ff = 0; ff < 4; ++ff) {
            int f = f0 + ff * 8;
            float2* row = img + (f >> 1) * 256 + (f & 1) * 128;
            float2 a = row[i0];
            float2 bb = row[i0 + s];
            float tx = bb.x * cs - bb.y * sn, ty = bb.x * sn + bb.y * cs;
            row[i0] = make_float2(a.x + tx, a.y + ty);
            row[i0 + s] = make_float2(a.x - tx, a.y - ty);
        }
        __syncthreads();
    }
    {   // final stage (s=64): write bf16 reals only
        float ang = PI_F * (float)j * (1.0f / 64.0f);
        float sn, cs;
        __sincosf(ang, &sn, &cs);
#pragma unroll
        for (int ff = 0; ff < 4; ++ff) {
            int f = f0 + ff * 8;
            int base = (f >> 1) * 256 + (f & 1) * 128;
            float2 a = img[base + j];
            float2 bb = img[base + j + 64];
            float tx = bb.x * cs - bb.y * sn;
            ebf[base + j]      = f2bf(a.x + tx);
            ebf[base + j + 64] = f2bf(a.x - tx);
        }
    }
    __syncthreads();
    int p4 = t & 63, cg = t >> 6;                 // cg in [0,8)
    u32x2_t ep[CMID];
    const u32x2_t* eb = (const u32x2_t*)ebf;
#pragma unroll
    for (int m = 0; m < CMID; ++m) ep[m] = eb[m * 64 + p4];
    const f32x4_t* xb = (const f32x4_t*)(x + (size_t)b * CIN * HWSZ) + (size_t)r0 * 32 + p4;
    f32x4_t* ob = (f32x4_t*)(out + (size_t)b * CIN * HWSZ) + (size_t)r0 * 32 + p4;
    int c0 = cg * 32;
    for (int c = c0; c < c0 + 32; c += 4) {
        f32x4_t a0 = xb[(size_t)(c + 0) * HW4];
        f32x4_t a1 = xb[(size_t)(c + 1) * HW4];
        f32x4_t a2 = xb[(size_t)(c + 2) * HW4];
        f32x4_t a3 = xb[(size_t)(c + 3) * HW4];
#pragma unroll
        for (int m = 0; m < CMID; ++m) {
            f32x4_t e = (f32x4_t){ bf_lo(ep[m].x), bf_hi(ep[m].x),
                                   bf_lo(ep[m].y), bf_hi(ep[m].y) };
            a0 += w_out[(c + 0) * CMID + m] * e;
            a1 += w_out[(c + 1) * CMID + m] * e;
            a2 += w_out[(c + 2) * CMID + m] * e;
            a3 += w_out[(c + 3) * CMID + m] * e;
        }
        __builtin_nontemporal_store(a0, ob + (size_t)(c + 0) * HW4);
        __builtin_nontemporal_store(a1, ob + (size_t)(c + 1) * HW4);
        __builtin_nontemporal_store(a2, ob + (size_t)(c + 2) * HW4);
        __builtin_nontemporal_store(a3, ob + (size_t)(c + 3) * HW4);
    }
}

extern "C" void kernel_launch(void* const* d_in, const int* in_sizes, int n_in,
                              void* d_out, int out_size, void* d_ws, size_t ws_size,
                              hipStream_t stream) {
    const float* x     = (const float*)d_in[0];
    const float* w_in  = (const float*)d_in[1];
    const float* w_out = (const float*)d_in[2];
    const float* fw    = (const float*)d_in[3];
    float* out = (float*)d_out;

    int nchunk = 8;
    while (nchunk > 1) {
        size_t need = (size_t)NB * nchunk * CMID * HWSZ * 2   // partials bf16
                    + (size_t)NB * CMID * HWSZ * 4            // xf bf16-complex
                    + (size_t)CMID * HWSZ * 4;                // gain fp32
        if (need <= ws_size) break;
        nchunk >>= 1;
    }
    unsigned short* partials = (unsigned short*)d_ws;
    unsigned* xfu = (unsigned*)(partials + (size_t)NB * nchunk * CMID * HWSZ);
    float*    gain = (float*)(xfu + (size_t)NB * CMID * HWSZ);

    gain_kernel<<<HWSZ / 256, 256, 0, stream>>>(fw, gain);
    proj_partial<<<dim3(HW4 / 256, nchunk, NB), 256, 0, stream>>>(x, w_in, partials, nchunk);
    reduce_fft_rows<<<dim3(NH / 4, NB * CMID), 256, 0, stream>>>(partials, xfu, nchunk);
    fft_cols_gain<<<dim3(NW / 32, NB * CMID), 256, 0, stream>>>(xfu, gain);
    ifft_out<<<dim3(NH / 2, NB), 512, 0, stream>>>(xfu, x, w_out, out);
}